// Round 9
// baseline (229.497 us; speedup 1.0000x reference)
//
#include <hip/hip_runtime.h>
#include <hip/hip_bf16.h>

// ---------------------------------------------------------------------------
// R16 = R15 + LDS-FREE Q/K transpose via identity-MFMA + no-max softmax:
//   - Q/K transpose (lane=ch -> lane=tok) done with D = A*Identity on the
//     matrix pipe: pack(2) + mfma(1) + pack(2) per tile replaces the LDS
//     round-trip (16 shfl + 16 packs + 16 ds_write + 8 ds_read + lgkm wait).
//     Kernel now uses ZERO LDS and ZERO barriers; only cross-lane ops left
//     are the LN/softmax butterflies.
//     Precision unchanged: bf16 value -> exact f32 copy -> bf16 repack is a
//     lossless round-trip (still exactly one rounding of Q/K).
//   - Softmax WITHOUT max subtraction: scores bounded (|q.k|*0.25*log2e < ~92
//     even with worst-case operator norms) so exp2(s) cannot overflow fp32 or
//     bf16 (exp range 127); softmax ratios are scale-invariant. Saves the max
//     tree + 2 butterflies + 16 subs per query tile.
// Layouts (16x16x16 v_mfma_f32_16x16x16bf16_1k, verified by R15 pass):
//   C/D: D[m=quad*4+reg][n=lane&15]
//   A:   A[m=lane&15][k=quad*4+j]   (word p = elems 2p(lo16), 2p+1(hi16))
//   B:   B[k=quad*4+j][n=lane&15]
// Identity-transpose: D[m][n] = sum_k A[m,k] I[k,n] = A[m,n] -> value moves
// from (lane=n-dim of A? no: lane=m of A) ... concretely: input packed with
// lane=c15 holding regs r=quad4+r of the OTHER index; output lane=c15 holds
// the transposed orientation. Verified algebra in comments at use site.
// ---------------------------------------------------------------------------

typedef __attribute__((ext_vector_type(4))) short bf4;   // 4 bf16 (2 VGPRs)
typedef __attribute__((ext_vector_type(4))) float f4;    // 4 fp32 (C/D frag)

union Frag2 { uint2 u2; uint u[2]; bf4 b; };
union F4U  { uint4 u4; float4 f; };

__device__ __forceinline__ uint packbf(float lo, float hi) {   // lo -> bits[15:0]
    union { __hip_bfloat162 h; uint u; } c;
    c.h = __float22bfloat162_rn(make_float2(lo, hi));
    return c.u;
}

// tanh-form gelu: u * sigma(2*sqrt(2/pi)*(u + 0.044715 u^3)), exp2 domain.
__device__ __forceinline__ float gelu_fast(float u) {
    float u2 = u * u;
    float t  = u * (-2.3022079f + -0.1029431f * u2);   // -2*log2e*c1*(1+c2 u^2)
    float e  = __builtin_amdgcn_exp2f(t);
    return u * __builtin_amdgcn_rcpf(1.f + e);
}

#define MFMA16(a, b, c) __builtin_amdgcn_mfma_f32_16x16x16bf16_1k(a, b, c, 0, 0, 0)

#define NWAVES 4

// ws blob: per-lane 16 uint4 slots (256 B/lane, 16 KB):
//  0: {fWq, fWk}  1: {fWv, fW1a}  2: {fW1b, fW2a}  3: {fW2b, -}
//  4: ln1g[q4..+3] 5: ln1b[q4..+3] 6: ln2g[q4..+3] 7: ln2b[q4..+3]
//  8: b1[q4..+3]   9: b1[16+q4..+3] 10: b2[q4..+3]
#define WS_SLOTS 16

// K=16 bf16 fragment (2 words): element k=q*4+2p(+1), column n, row-major W.
// Serves as B[k][n] or A[m=n][k] (identical lane/word mapping).
__device__ __forceinline__ uint2 wfrag16(const float* __restrict__ W, int ld,
                                         int n, int q, float s) {
    uint2 w;
    w.x = packbf(W[(q*4+0)*ld+n]*s, W[(q*4+1)*ld+n]*s);
    w.y = packbf(W[(q*4+2)*ld+n]*s, W[(q*4+3)*ld+n]*s);
    return w;
}

__global__ __launch_bounds__(64, 1)
void prep_kernel(const float* __restrict__ Wk, const float* __restrict__ Wq,
                 const float* __restrict__ Wv,
                 const float* __restrict__ ln1g, const float* __restrict__ ln1b,
                 const float* __restrict__ ln2g, const float* __restrict__ ln2b,
                 const float* __restrict__ W1, const float* __restrict__ b1,
                 const float* __restrict__ W2, const float* __restrict__ b2,
                 uint4* __restrict__ ws)
{
    const int lane = threadIdx.x;
    const int c15  = lane & 15;
    const int quad = lane >> 4;
    const int quad4 = quad << 2;
    uint4* o = ws + lane * WS_SLOTS;
    // Wq folds 1/sqrt(16) and log2(e): scores land in log2 domain.
    uint2 fq  = wfrag16(Wq, 16, c15, quad, 0.25f*1.44269504f);
    uint2 fk  = wfrag16(Wk, 16, c15, quad, 1.0f);
    uint2 fv  = wfrag16(Wv, 16, c15, quad, 1.0f);
    uint2 f1a = wfrag16(W1, 32, c15,      quad, 1.0f);  // A[m=ff(c15)][k=ch]
    uint2 f1b = wfrag16(W1, 32, c15 + 16, quad, 1.0f);  // A[m=ff(16+c15)][k=ch]
    uint2 f2a = wfrag16(W2,        16, c15, quad, 1.0f); // A[m=ch][k=ff 0..15]
    uint2 f2b = wfrag16(W2 + 256,  16, c15, quad, 1.0f); // A[m=ch][k=ff 16..31]
    o[0] = make_uint4(fq.x, fq.y, fk.x, fk.y);
    o[1] = make_uint4(fv.x, fv.y, f1a.x, f1a.y);
    o[2] = make_uint4(f1b.x, f1b.y, f2a.x, f2a.y);
    o[3] = make_uint4(f2b.x, f2b.y, 0u, 0u);
    F4U a;
    a.f = *(const float4*)(ln1g + quad4); o[4]  = a.u4;
    a.f = *(const float4*)(ln1b + quad4); o[5]  = a.u4;
    a.f = *(const float4*)(ln2g + quad4); o[6]  = a.u4;
    a.f = *(const float4*)(ln2b + quad4); o[7]  = a.u4;
    a.f = *(const float4*)(b1 + quad4);      o[8]  = a.u4;
    a.f = *(const float4*)(b1 + 16 + quad4); o[9]  = a.u4;
    a.f = *(const float4*)(b2 + quad4);      o[10] = a.u4;
}

__global__ __launch_bounds__(64 * NWAVES, 8)
void tb_kernel(const float* __restrict__ x,
               const uint4* __restrict__ ws,
               float* __restrict__ out)
{
    const int tid  = threadIdx.x;
    const int lane = tid & 63;
    const int wid  = tid >> 6;
    const int c15  = lane & 15;
    const int quad = lane >> 4;
    const int quad4 = quad << 2;
    const size_t base = (size_t)(blockIdx.x * NWAVES + wid) * (64 * 16);
    const f4 z4 = {0.f, 0.f, 0.f, 0.f};

    // ---- x read ONCE: [tok=qt*16+c15][ch=quad4..+3] feeds LN1 AND residual
    float4 xr[4];
    #pragma unroll
    for (int qt = 0; qt < 4; ++qt)
        xr[qt] = *(const float4*)(x + base + (size_t)(qt*16 + c15)*16 + quad4);

    // ---- prologue: 11 b128 loads from the pre-packed blob (L2-hot)
    const uint4* wv = ws + lane * WS_SLOTS;
    uint4 s0 = wv[0], s1 = wv[1], s2 = wv[2], s3 = wv[3];
    Frag2 T;
    T.u[0]=s0.x; T.u[1]=s0.y; const bf4 fWq  = T.b;
    T.u[0]=s0.z; T.u[1]=s0.w; const bf4 fWk  = T.b;
    T.u[0]=s1.x; T.u[1]=s1.y; const bf4 fWv  = T.b;
    T.u[0]=s1.z; T.u[1]=s1.w; const bf4 fW1a = T.b;
    T.u[0]=s2.x; T.u[1]=s2.y; const bf4 fW1b = T.b;
    T.u[0]=s2.z; T.u[1]=s2.w; const bf4 fW2a = T.b;
    T.u[0]=s3.x; T.u[1]=s3.y; const bf4 fW2b = T.b;
    F4U fu;
    fu.u4 = wv[4];  const float4 g1  = fu.f;
    fu.u4 = wv[5];  const float4 b1l = fu.f;
    fu.u4 = wv[6];  const float4 g2  = fu.f;
    fu.u4 = wv[7];  const float4 b2l = fu.f;
    fu.u4 = wv[8];  const f4 cb0 = {fu.f.x, fu.f.y, fu.f.z, fu.f.w};  // b1[ff q4+r]
    fu.u4 = wv[9];  const f4 cb1 = {fu.f.x, fu.f.y, fu.f.z, fu.f.w};  // b1[16+q4+r]
    fu.u4 = wv[10]; const f4 cb2 = {fu.f.x, fu.f.y, fu.f.z, fu.f.w};  // b2[q4+r]

    // ---- identity fragment (bf16 one = 0x3F80): I[k=quad*4+j][n=c15]
    //  word p covers k = quad*4+2p (lo16) and quad*4+2p+1 (hi16)
    bf4 idf;
    {
        const int d = c15 - quad4;
        Frag2 I_;
        I_.u[0] = (d == 0) ? 0x00003F80u : (d == 1) ? 0x3F800000u : 0u;
        I_.u[1] = (d == 2) ? 0x00003F80u : (d == 3) ? 0x3F800000u : 0u;
        idf = I_.b;
    }

    // ---- LN1 (all 64 lanes, two-pass variance) -> A-frags in-lane
    bf4 ah[4];
    #pragma unroll
    for (int qt = 0; qt < 4; ++qt) {
        float4 v = xr[qt];
        float s = v.x + v.y + v.z + v.w;
        s += __shfl_xor(s, 16); s += __shfl_xor(s, 32);
        float mu = s * 0.0625f;
        float d0 = v.x-mu, d1 = v.y-mu, d2 = v.z-mu, d3 = v.w-mu;
        float s2 = d0*d0 + d1*d1 + d2*d2 + d3*d3;
        s2 += __shfl_xor(s2, 16); s2 += __shfl_xor(s2, 32);
        float rstd = rsqrtf(s2 * 0.0625f + 1e-5f);
        float h0 = d0*rstd*g1.x + b1l.x;
        float h1 = d1*rstd*g1.y + b1l.y;
        float h2 = d2*rstd*g1.z + b1l.z;
        float h3 = d3*rstd*g1.w + b1l.w;
        Frag2 A; A.u[0] = packbf(h0, h1); A.u[1] = packbf(h2, h3);
        ah[qt] = A.b;     // A[m=tok(c15)][k=ch(quad*4+j)] for tile qt
    }

    // ---- projections (12 MFMA16) + identity-MFMA transposes (8 MFMA16)
    //  qc/kc: D[m=tok=quad4+r][n=ch=c15]  (lane=ch)
    //  pack as A[m=ch(c15)][k=tok(quad*4+j)] -> D2 = A*I: lane=tok, reg=ch
    //  -> pack Q as B[k=ch(quad*4+j)][n=query(c15)], K as A[m=key][k=ch]
    bf4 va[4], ka[4], qb[4];
    #pragma unroll
    for (int mt = 0; mt < 4; ++mt) {
        f4 qc = MFMA16(ah[mt], fWq, z4);
        f4 kc = MFMA16(ah[mt], fWk, z4);
        f4 vc = MFMA16(ah[mt], fWv, z4);
        Frag2 Aq, Ak, V_;
        Aq.u[0] = packbf(qc[0], qc[1]); Aq.u[1] = packbf(qc[2], qc[3]);
        Ak.u[0] = packbf(kc[0], kc[1]); Ak.u[1] = packbf(kc[2], kc[3]);
        V_.u[0] = packbf(vc[0], vc[1]); V_.u[1] = packbf(vc[2], vc[3]);
        va[mt] = V_.b;                 // A[m=ch(c15)][k=key(quad*4+j)]
        f4 tq = MFMA16(Aq.b, idf, z4); // D[m=ch=quad4+r][n=tok=c15] (exact copy)
        f4 tk = MFMA16(Ak.b, idf, z4);
        Frag2 Qb, Ka;
        Qb.u[0] = packbf(tq[0], tq[1]); Qb.u[1] = packbf(tq[2], tq[3]);
        Ka.u[0] = packbf(tk[0], tk[1]); Ka.u[1] = packbf(tk[2], tk[3]);
        qb[mt] = Qb.b;                 // B[k=ch(quad*4+j)][n=query(c15)]
        ka[mt] = Ka.b;                 // A[m=key(c15)][k=ch(quad*4+j)]
    }

    // ---- S^T = K.Q^T, causal triangle (10 MFMA16); log2-domain scores
    f4 st[4][4];   // st[kt][qt]: S^T[key=kt*16+quad4+r][query=qt*16+c15]
    #pragma unroll
    for (int kt = 0; kt < 4; ++kt)
        #pragma unroll
        for (int qt = 3; qt >= 0; --qt)
            if (qt >= kt)
                st[kt][qt] = MFMA16(ka[kt], qb[qt], z4);
    #pragma unroll
    for (int qt = 0; qt < 4; ++qt)
        #pragma unroll
        for (int r = 0; r < 4; ++r)
            st[qt][qt][r] = (quad4 + r <= c15) ? st[qt][qt][r] : -1e30f;

    // ---- softmax WITHOUT max subtraction (scores bounded; exp2 can't
    //      overflow fp32/bf16; ratios scale-invariant). masked -> exp2(-1e30)=0
    float linv[4];
    #pragma unroll
    for (int qt = 0; qt < 4; ++qt) {
        float l = 0.f;
        #pragma unroll
        for (int kt = 0; kt < 4; ++kt) {
            if (kt <= qt) {
                #pragma unroll
                for (int r = 0; r < 4; ++r) {
                    float p = __builtin_amdgcn_exp2f(st[kt][qt][r]);
                    st[kt][qt][r] = p;
                    l += p;
                }
            }
        }
        l += __shfl_xor(l, 16);
        l += __shfl_xor(l, 32);
        linv[qt] = __builtin_amdgcn_rcpf(l);
    }

    // ---- PV entirely in-register: y^T[qt] = sum_kt MFMA16(va[kt], P-frag)
    f4 yt[4];
    #pragma unroll
    for (int qt = 0; qt < 4; ++qt) {
        f4 acc = z4;
        #pragma unroll
        for (int kt = 0; kt < 4; ++kt) {
            if (kt <= qt) {
                Frag2 P_;              // B[k=key(quad*4+j)][n=query(c15)]
                P_.u[0] = packbf(st[kt][qt][0], st[kt][qt][1]);
                P_.u[1] = packbf(st[kt][qt][2], st[kt][qt][3]);
                acc = MFMA16(va[kt], P_.b, acc);
            }
        }
        yt[qt] = acc;                  // D[m=ch=quad4+r][n=query=qt*16+c15]
    }

    // ---- residual 1 + LN2 + FFN (all in-register; no LDS anywhere)
    float x2v[4][4];
    f4 uu0[4], uu1[4];
    #pragma unroll
    for (int qt = 0; qt < 4; ++qt) {
        const float li = linv[qt];
        x2v[qt][0] = xr[qt].x + yt[qt][0]*li;
        x2v[qt][1] = xr[qt].y + yt[qt][1]*li;
        x2v[qt][2] = xr[qt].z + yt[qt][2]*li;
        x2v[qt][3] = xr[qt].w + yt[qt][3]*li;
        // LN2 (two-pass, cross-quad butterfly)
        float s = x2v[qt][0]+x2v[qt][1]+x2v[qt][2]+x2v[qt][3];
        s += __shfl_xor(s, 16); s += __shfl_xor(s, 32);
        float mu = s * 0.0625f;
        float d0 = x2v[qt][0]-mu, d1 = x2v[qt][1]-mu,
              d2 = x2v[qt][2]-mu, d3 = x2v[qt][3]-mu;
        float s2 = d0*d0 + d1*d1 + d2*d2 + d3*d3;
        s2 += __shfl_xor(s2, 16); s2 += __shfl_xor(s2, 32);
        float rstd = rsqrtf(s2 * 0.0625f + 1e-5f);
        float h0 = d0*rstd*g2.x + b2l.x;
        float h1 = d1*rstd*g2.y + b2l.y;
        float h2 = d2*rstd*g2.z + b2l.z;
        float h3 = d3*rstd*g2.w + b2l.w;
        Frag2 Hb;                      // B[k=ch(quad*4+j)][n=tok(c15)]
        Hb.u[0] = packbf(h0, h1); Hb.u[1] = packbf(h2, h3);
        // FFN1 transposed: U^T = W1^T.h2^T   D[m=ff=quad4+r][n=tok]
        uu0[qt] = MFMA16(fW1a, Hb.b, cb0);
        uu1[qt] = MFMA16(fW1b, Hb.b, cb1);
    }
    #pragma unroll
    for (int qt = 0; qt < 4; ++qt) {
        Frag2 Pa, Pb;                  // B[k=ff(quad*4+j)][n=tok(c15)]
        Pa.u[0] = packbf(gelu_fast(uu0[qt][0]), gelu_fast(uu0[qt][1]));
        Pa.u[1] = packbf(gelu_fast(uu0[qt][2]), gelu_fast(uu0[qt][3]));
        Pb.u[0] = packbf(gelu_fast(uu1[qt][0]), gelu_fast(uu1[qt][1]));
        Pb.u[1] = packbf(gelu_fast(uu1[qt][2]), gelu_fast(uu1[qt][3]));
        // FFN2 transposed, K=32 as two K=16 chunks -> direct store layout
        f4 fo = MFMA16(fW2a, Pa.b, cb2);
        fo = MFMA16(fW2b, Pb.b, fo);   // D[m=ch=quad4+r][n=tok=qt*16+c15]
        float4 o;
        o.x = x2v[qt][0] + fo[0];
        o.y = x2v[qt][1] + fo[1];
        o.z = x2v[qt][2] + fo[2];
        o.w = x2v[qt][3] + fo[3];
        *(float4*)(out + base + (size_t)(qt*16 + c15)*16 + quad4) = o;
    }
}

extern "C" void kernel_launch(void* const* d_in, const int* in_sizes, int n_in,
                              void* d_out, int out_size, void* d_ws, size_t ws_size,
                              hipStream_t stream) {
    const float* x     = (const float*)d_in[0];
    const float* Wk    = (const float*)d_in[1];
    const float* Wq    = (const float*)d_in[2];
    const float* Wv    = (const float*)d_in[3];
    const float* ln1_g = (const float*)d_in[4];
    const float* ln1_b = (const float*)d_in[5];
    const float* ln2_g = (const float*)d_in[6];
    const float* ln2_b = (const float*)d_in[7];
    const float* W1    = (const float*)d_in[8];
    const float* b1    = (const float*)d_in[9];
    const float* W2    = (const float*)d_in[10];
    const float* b2    = (const float*)d_in[11];
    float* out = (float*)d_out;
    uint4* ws = (uint4*)d_ws;

    prep_kernel<<<1, 64, 0, stream>>>(Wk, Wq, Wv, ln1_g, ln1_b, ln2_g, ln2_b,
                                      W1, b1, W2, b2, ws);
    const int n_blocks = in_sizes[0] / (64 * 16);       // 16384
    const int nwg = n_blocks / NWAVES;                  // 4096 wgs x 256 thr
    tb_kernel<<<nwg, 64 * NWAVES, 0, stream>>>(x, ws, out);
}

// Round 10
// 148.923 us; speedup vs baseline: 1.5410x; 1.5410x over previous
//
#include <hip/hip_runtime.h>
#include <hip/hip_bf16.h>

// ---------------------------------------------------------------------------
// R17 = R16 with launch_bounds restored to (256, 4).
// R16's (256, 8) forced the register allocator to 32 VGPRs -> massive scratch
// spills (WRITE_SIZE 65->245 MB, FETCH 33->117 MB, 126 us). The structural
// changes themselves PASSED accuracy and are kept:
//   - ZERO LDS / ZERO barriers: Q/K transpose via identity-MFMA on the
//     matrix pipe (pack+mfma+pack replaces the LDS round-trip).
//   - no-max softmax (scores bounded; exp2 can't overflow; ratios invariant).
//   - K=16 fragment composition throughout (R15): V/P/h2/U hand-offs in-lane.
//   - prep kernel pre-packs weights/ln/biases; x read once; transposed FFN.
// Layouts (16x16x16 v_mfma_f32_16x16x16bf16_1k, verified R15/R16 pass):
//   C/D: D[m=quad*4+reg][n=lane&15]
//   A:   A[m=lane&15][k=quad*4+j]   (word p = elems 2p(lo16), 2p+1(hi16))
//   B:   B[k=quad*4+j][n=lane&15]
// ---------------------------------------------------------------------------

typedef __attribute__((ext_vector_type(4))) short bf4;   // 4 bf16 (2 VGPRs)
typedef __attribute__((ext_vector_type(4))) float f4;    // 4 fp32 (C/D frag)

union Frag2 { uint2 u2; uint u[2]; bf4 b; };
union F4U  { uint4 u4; float4 f; };

__device__ __forceinline__ uint packbf(float lo, float hi) {   // lo -> bits[15:0]
    union { __hip_bfloat162 h; uint u; } c;
    c.h = __float22bfloat162_rn(make_float2(lo, hi));
    return c.u;
}

// tanh-form gelu: u * sigma(2*sqrt(2/pi)*(u + 0.044715 u^3)), exp2 domain.
__device__ __forceinline__ float gelu_fast(float u) {
    float u2 = u * u;
    float t  = u * (-2.3022079f + -0.1029431f * u2);   // -2*log2e*c1*(1+c2 u^2)
    float e  = __builtin_amdgcn_exp2f(t);
    return u * __builtin_amdgcn_rcpf(1.f + e);
}

#define MFMA16(a, b, c) __builtin_amdgcn_mfma_f32_16x16x16bf16_1k(a, b, c, 0, 0, 0)

#define NWAVES 4

// ws blob: per-lane 16 uint4 slots (256 B/lane, 16 KB):
//  0: {fWq, fWk}  1: {fWv, fW1a}  2: {fW1b, fW2a}  3: {fW2b, -}
//  4: ln1g[q4..+3] 5: ln1b[q4..+3] 6: ln2g[q4..+3] 7: ln2b[q4..+3]
//  8: b1[q4..+3]   9: b1[16+q4..+3] 10: b2[q4..+3]
#define WS_SLOTS 16

// K=16 bf16 fragment (2 words): element k=q*4+2p(+1), column n, row-major W.
// Serves as B[k][n] or A[m=n][k] (identical lane/word mapping).
__device__ __forceinline__ uint2 wfrag16(const float* __restrict__ W, int ld,
                                         int n, int q, float s) {
    uint2 w;
    w.x = packbf(W[(q*4+0)*ld+n]*s, W[(q*4+1)*ld+n]*s);
    w.y = packbf(W[(q*4+2)*ld+n]*s, W[(q*4+3)*ld+n]*s);
    return w;
}

__global__ __launch_bounds__(64, 1)
void prep_kernel(const float* __restrict__ Wk, const float* __restrict__ Wq,
                 const float* __restrict__ Wv,
                 const float* __restrict__ ln1g, const float* __restrict__ ln1b,
                 const float* __restrict__ ln2g, const float* __restrict__ ln2b,
                 const float* __restrict__ W1, const float* __restrict__ b1,
                 const float* __restrict__ W2, const float* __restrict__ b2,
                 uint4* __restrict__ ws)
{
    const int lane = threadIdx.x;
    const int c15  = lane & 15;
    const int quad = lane >> 4;
    const int quad4 = quad << 2;
    uint4* o = ws + lane * WS_SLOTS;
    // Wq folds 1/sqrt(16) and log2(e): scores land in log2 domain.
    uint2 fq  = wfrag16(Wq, 16, c15, quad, 0.25f*1.44269504f);
    uint2 fk  = wfrag16(Wk, 16, c15, quad, 1.0f);
    uint2 fv  = wfrag16(Wv, 16, c15, quad, 1.0f);
    uint2 f1a = wfrag16(W1, 32, c15,      quad, 1.0f);  // A[m=ff(c15)][k=ch]
    uint2 f1b = wfrag16(W1, 32, c15 + 16, quad, 1.0f);  // A[m=ff(16+c15)][k=ch]
    uint2 f2a = wfrag16(W2,        16, c15, quad, 1.0f); // A[m=ch][k=ff 0..15]
    uint2 f2b = wfrag16(W2 + 256,  16, c15, quad, 1.0f); // A[m=ch][k=ff 16..31]
    o[0] = make_uint4(fq.x, fq.y, fk.x, fk.y);
    o[1] = make_uint4(fv.x, fv.y, f1a.x, f1a.y);
    o[2] = make_uint4(f1b.x, f1b.y, f2a.x, f2a.y);
    o[3] = make_uint4(f2b.x, f2b.y, 0u, 0u);
    F4U a;
    a.f = *(const float4*)(ln1g + quad4); o[4]  = a.u4;
    a.f = *(const float4*)(ln1b + quad4); o[5]  = a.u4;
    a.f = *(const float4*)(ln2g + quad4); o[6]  = a.u4;
    a.f = *(const float4*)(ln2b + quad4); o[7]  = a.u4;
    a.f = *(const float4*)(b1 + quad4);      o[8]  = a.u4;
    a.f = *(const float4*)(b1 + 16 + quad4); o[9]  = a.u4;
    a.f = *(const float4*)(b2 + quad4);      o[10] = a.u4;
}

__global__ __launch_bounds__(64 * NWAVES, 4)
void tb_kernel(const float* __restrict__ x,
               const uint4* __restrict__ ws,
               float* __restrict__ out)
{
    const int tid  = threadIdx.x;
    const int lane = tid & 63;
    const int wid  = tid >> 6;
    const int c15  = lane & 15;
    const int quad = lane >> 4;
    const int quad4 = quad << 2;
    const size_t base = (size_t)(blockIdx.x * NWAVES + wid) * (64 * 16);
    const f4 z4 = {0.f, 0.f, 0.f, 0.f};

    // ---- x read ONCE: [tok=qt*16+c15][ch=quad4..+3] feeds LN1 AND residual
    float4 xr[4];
    #pragma unroll
    for (int qt = 0; qt < 4; ++qt)
        xr[qt] = *(const float4*)(x + base + (size_t)(qt*16 + c15)*16 + quad4);

    // ---- prologue: 11 b128 loads from the pre-packed blob (L2-hot)
    const uint4* wv = ws + lane * WS_SLOTS;
    uint4 s0 = wv[0], s1 = wv[1], s2 = wv[2], s3 = wv[3];
    Frag2 T;
    T.u[0]=s0.x; T.u[1]=s0.y; const bf4 fWq  = T.b;
    T.u[0]=s0.z; T.u[1]=s0.w; const bf4 fWk  = T.b;
    T.u[0]=s1.x; T.u[1]=s1.y; const bf4 fWv  = T.b;
    T.u[0]=s1.z; T.u[1]=s1.w; const bf4 fW1a = T.b;
    T.u[0]=s2.x; T.u[1]=s2.y; const bf4 fW1b = T.b;
    T.u[0]=s2.z; T.u[1]=s2.w; const bf4 fW2a = T.b;
    T.u[0]=s3.x; T.u[1]=s3.y; const bf4 fW2b = T.b;
    F4U fu;
    fu.u4 = wv[4];  const float4 g1  = fu.f;
    fu.u4 = wv[5];  const float4 b1l = fu.f;
    fu.u4 = wv[6];  const float4 g2  = fu.f;
    fu.u4 = wv[7];  const float4 b2l = fu.f;
    fu.u4 = wv[8];  const f4 cb0 = {fu.f.x, fu.f.y, fu.f.z, fu.f.w};  // b1[ff q4+r]
    fu.u4 = wv[9];  const f4 cb1 = {fu.f.x, fu.f.y, fu.f.z, fu.f.w};  // b1[16+q4+r]
    fu.u4 = wv[10]; const f4 cb2 = {fu.f.x, fu.f.y, fu.f.z, fu.f.w};  // b2[q4+r]

    // ---- identity fragment (bf16 one = 0x3F80): I[k=quad*4+j][n=c15]
    //  word p covers k = quad*4+2p (lo16) and quad*4+2p+1 (hi16)
    bf4 idf;
    {
        const int d = c15 - quad4;
        Frag2 I_;
        I_.u[0] = (d == 0) ? 0x00003F80u : (d == 1) ? 0x3F800000u : 0u;
        I_.u[1] = (d == 2) ? 0x00003F80u : (d == 3) ? 0x3F800000u : 0u;
        idf = I_.b;
    }

    // ---- LN1 (all 64 lanes, two-pass variance) -> A-frags in-lane
    bf4 ah[4];
    #pragma unroll
    for (int qt = 0; qt < 4; ++qt) {
        float4 v = xr[qt];
        float s = v.x + v.y + v.z + v.w;
        s += __shfl_xor(s, 16); s += __shfl_xor(s, 32);
        float mu = s * 0.0625f;
        float d0 = v.x-mu, d1 = v.y-mu, d2 = v.z-mu, d3 = v.w-mu;
        float s2 = d0*d0 + d1*d1 + d2*d2 + d3*d3;
        s2 += __shfl_xor(s2, 16); s2 += __shfl_xor(s2, 32);
        float rstd = rsqrtf(s2 * 0.0625f + 1e-5f);
        float h0 = d0*rstd*g1.x + b1l.x;
        float h1 = d1*rstd*g1.y + b1l.y;
        float h2 = d2*rstd*g1.z + b1l.z;
        float h3 = d3*rstd*g1.w + b1l.w;
        Frag2 A; A.u[0] = packbf(h0, h1); A.u[1] = packbf(h2, h3);
        ah[qt] = A.b;     // A[m=tok(c15)][k=ch(quad*4+j)] for tile qt
    }

    // ---- projections (12 MFMA16) + identity-MFMA transposes (8 MFMA16)
    //  qc/kc: D[m=tok=quad4+r][n=ch=c15]  (lane=ch)
    //  pack as A[m=ch(c15)][k=tok(quad*4+j)] -> D2 = A*I: lane=tok, reg=ch
    //  -> pack Q as B[k=ch(quad*4+j)][n=query(c15)], K as A[m=key][k=ch]
    bf4 va[4], ka[4], qb[4];
    #pragma unroll
    for (int mt = 0; mt < 4; ++mt) {
        f4 qc = MFMA16(ah[mt], fWq, z4);
        f4 kc = MFMA16(ah[mt], fWk, z4);
        f4 vc = MFMA16(ah[mt], fWv, z4);
        Frag2 Aq, Ak, V_;
        Aq.u[0] = packbf(qc[0], qc[1]); Aq.u[1] = packbf(qc[2], qc[3]);
        Ak.u[0] = packbf(kc[0], kc[1]); Ak.u[1] = packbf(kc[2], kc[3]);
        V_.u[0] = packbf(vc[0], vc[1]); V_.u[1] = packbf(vc[2], vc[3]);
        va[mt] = V_.b;                 // A[m=ch(c15)][k=key(quad*4+j)]
        f4 tq = MFMA16(Aq.b, idf, z4); // D[m=ch=quad4+r][n=tok=c15] (exact copy)
        f4 tk = MFMA16(Ak.b, idf, z4);
        Frag2 Qb, Ka;
        Qb.u[0] = packbf(tq[0], tq[1]); Qb.u[1] = packbf(tq[2], tq[3]);
        Ka.u[0] = packbf(tk[0], tk[1]); Ka.u[1] = packbf(tk[2], tk[3]);
        qb[mt] = Qb.b;                 // B[k=ch(quad*4+j)][n=query(c15)]
        ka[mt] = Ka.b;                 // A[m=key(c15)][k=ch(quad*4+j)]
    }

    // ---- S^T = K.Q^T, causal triangle (10 MFMA16); log2-domain scores
    f4 st[4][4];   // st[kt][qt]: S^T[key=kt*16+quad4+r][query=qt*16+c15]
    #pragma unroll
    for (int kt = 0; kt < 4; ++kt)
        #pragma unroll
        for (int qt = 3; qt >= 0; --qt)
            if (qt >= kt)
                st[kt][qt] = MFMA16(ka[kt], qb[qt], z4);
    #pragma unroll
    for (int qt = 0; qt < 4; ++qt)
        #pragma unroll
        for (int r = 0; r < 4; ++r)
            st[qt][qt][r] = (quad4 + r <= c15) ? st[qt][qt][r] : -1e30f;

    // ---- softmax WITHOUT max subtraction (scores bounded; exp2 can't
    //      overflow fp32/bf16; ratios scale-invariant). masked -> exp2(-1e30)=0
    float linv[4];
    #pragma unroll
    for (int qt = 0; qt < 4; ++qt) {
        float l = 0.f;
        #pragma unroll
        for (int kt = 0; kt < 4; ++kt) {
            if (kt <= qt) {
                #pragma unroll
                for (int r = 0; r < 4; ++r) {
                    float p = __builtin_amdgcn_exp2f(st[kt][qt][r]);
                    st[kt][qt][r] = p;
                    l += p;
                }
            }
        }
        l += __shfl_xor(l, 16);
        l += __shfl_xor(l, 32);
        linv[qt] = __builtin_amdgcn_rcpf(l);
    }

    // ---- PV entirely in-register: y^T[qt] = sum_kt MFMA16(va[kt], P-frag)
    f4 yt[4];
    #pragma unroll
    for (int qt = 0; qt < 4; ++qt) {
        f4 acc = z4;
        #pragma unroll
        for (int kt = 0; kt < 4; ++kt) {
            if (kt <= qt) {
                Frag2 P_;              // B[k=key(quad*4+j)][n=query(c15)]
                P_.u[0] = packbf(st[kt][qt][0], st[kt][qt][1]);
                P_.u[1] = packbf(st[kt][qt][2], st[kt][qt][3]);
                acc = MFMA16(va[kt], P_.b, acc);
            }
        }
        yt[qt] = acc;                  // D[m=ch=quad4+r][n=query=qt*16+c15]
    }

    // ---- residual 1 + LN2 + FFN (all in-register; no LDS anywhere)
    float x2v[4][4];
    f4 uu0[4], uu1[4];
    #pragma unroll
    for (int qt = 0; qt < 4; ++qt) {
        const float li = linv[qt];
        x2v[qt][0] = xr[qt].x + yt[qt][0]*li;
        x2v[qt][1] = xr[qt].y + yt[qt][1]*li;
        x2v[qt][2] = xr[qt].z + yt[qt][2]*li;
        x2v[qt][3] = xr[qt].w + yt[qt][3]*li;
        // LN2 (two-pass, cross-quad butterfly)
        float s = x2v[qt][0]+x2v[qt][1]+x2v[qt][2]+x2v[qt][3];
        s += __shfl_xor(s, 16); s += __shfl_xor(s, 32);
        float mu = s * 0.0625f;
        float d0 = x2v[qt][0]-mu, d1 = x2v[qt][1]-mu,
              d2 = x2v[qt][2]-mu, d3 = x2v[qt][3]-mu;
        float s2 = d0*d0 + d1*d1 + d2*d2 + d3*d3;
        s2 += __shfl_xor(s2, 16); s2 += __shfl_xor(s2, 32);
        float rstd = rsqrtf(s2 * 0.0625f + 1e-5f);
        float h0 = d0*rstd*g2.x + b2l.x;
        float h1 = d1*rstd*g2.y + b2l.y;
        float h2 = d2*rstd*g2.z + b2l.z;
        float h3 = d3*rstd*g2.w + b2l.w;
        Frag2 Hb;                      // B[k=ch(quad*4+j)][n=tok(c15)]
        Hb.u[0] = packbf(h0, h1); Hb.u[1] = packbf(h2, h3);
        // FFN1 transposed: U^T = W1^T.h2^T   D[m=ff=quad4+r][n=tok]
        uu0[qt] = MFMA16(fW1a, Hb.b, cb0);
        uu1[qt] = MFMA16(fW1b, Hb.b, cb1);
    }
    #pragma unroll
    for (int qt = 0; qt < 4; ++qt) {
        Frag2 Pa, Pb;                  // B[k=ff(quad*4+j)][n=tok(c15)]
        Pa.u[0] = packbf(gelu_fast(uu0[qt][0]), gelu_fast(uu0[qt][1]));
        Pa.u[1] = packbf(gelu_fast(uu0[qt][2]), gelu_fast(uu0[qt][3]));
        Pb.u[0] = packbf(gelu_fast(uu1[qt][0]), gelu_fast(uu1[qt][1]));
        Pb.u[1] = packbf(gelu_fast(uu1[qt][2]), gelu_fast(uu1[qt][3]));
        // FFN2 transposed, K=32 as two K=16 chunks -> direct store layout
        f4 fo = MFMA16(fW2a, Pa.b, cb2);
        fo = MFMA16(fW2b, Pb.b, fo);   // D[m=ch=quad4+r][n=tok=qt*16+c15]
        float4 o;
        o.x = x2v[qt][0] + fo[0];
        o.y = x2v[qt][1] + fo[1];
        o.z = x2v[qt][2] + fo[2];
        o.w = x2v[qt][3] + fo[3];
        *(float4*)(out + base + (size_t)(qt*16 + c15)*16 + quad4) = o;
    }
}

extern "C" void kernel_launch(void* const* d_in, const int* in_sizes, int n_in,
                              void* d_out, int out_size, void* d_ws, size_t ws_size,
                              hipStream_t stream) {
    const float* x     = (const float*)d_in[0];
    const float* Wk    = (const float*)d_in[1];
    const float* Wq    = (const float*)d_in[2];
    const float* Wv    = (const float*)d_in[3];
    const float* ln1_g = (const float*)d_in[4];
    const float* ln1_b = (const float*)d_in[5];
    const float* ln2_g = (const float*)d_in[6];
    const float* ln2_b = (const float*)d_in[7];
    const float* W1    = (const float*)d_in[8];
    const float* b1    = (const float*)d_in[9];
    const float* W2    = (const float*)d_in[10];
    const float* b2    = (const float*)d_in[11];
    float* out = (float*)d_out;
    uint4* ws = (uint4*)d_ws;

    prep_kernel<<<1, 64, 0, stream>>>(Wk, Wq, Wv, ln1_g, ln1_b, ln2_g, ln2_b,
                                      W1, b1, W2, b2, ws);
    const int n_blocks = in_sizes[0] / (64 * 16);       // 16384
    const int nwg = n_blocks / NWAVES;                  // 4096 wgs x 256 thr
    tb_kernel<<<nwg, 64 * NWAVES, 0, stream>>>(x, ws, out);
}